// Round 3
// baseline (951.861 us; speedup 1.0000x reference)
//
#include <hip/hip_runtime.h>

typedef unsigned short u16;
typedef unsigned int u32;
typedef short bf16x8 __attribute__((ext_vector_type(8)));   // 8 bf16 (4 VGPRs)
typedef float f32x4 __attribute__((ext_vector_type(4)));

#define NB   64
#define NC   256
#define NO   256     // conv1 out channels
#define NM   1024    // LF*LF
#define PW   44      // padded width (32 + 2*6)
#define PPIX 1936    // 44*44

__device__ __forceinline__ u16 f2bf(float f) {
    u32 u = __builtin_bit_cast(u32, f);
    u32 r = (u + 0x7FFFu + ((u >> 16) & 1u)) >> 16;   // RNE
    return (u16)r;
}

// ---------- x[b][c][ij] (f32) -> xp[b][padded pix][c] (bf16), zero border (memset'd) ----------
__global__ __launch_bounds__(256) void k_transpose_pad(const float* __restrict__ x, u16* __restrict__ xp) {
    __shared__ u16 tile[64 * 65];
    const int b = blockIdx.z, ij0 = blockIdx.x * 64, c0 = blockIdx.y * 64;
    const int tid = threadIdx.x;
#pragma unroll
    for (int it = 0; it < 16; ++it) {
        int idx = it * 256 + tid;
        int cr = idx >> 6, ijr = idx & 63;
        tile[ijr * 65 + cr] = f2bf(x[((size_t)(b * NC + c0 + cr) << 10) + ij0 + ijr]);
    }
    __syncthreads();
#pragma unroll
    for (int it = 0; it < 16; ++it) {
        int idx = it * 256 + tid;
        int ijr = idx >> 6, cr = idx & 63;
        int pix = ij0 + ijr;
        int i = pix >> 5, j = pix & 31;
        int prow = (i + 6) * PW + (j + 6);
        xp[((size_t)(b * PPIX + prow) << 8) + c0 + cr] = tile[ijr * 65 + cr];
    }
}

// ---------- conv1_w (O,C,7,7) f32 -> w1t[tap][o][c] bf16 ----------
__global__ __launch_bounds__(256) void k_w1prep(const float* __restrict__ w1, u16* __restrict__ w1t) {
    const int o = blockIdx.x, c = threadIdx.x;
    const float* src = w1 + ((size_t)(o * NC + c)) * 49;
#pragma unroll
    for (int t = 0; t < 49; ++t)
        w1t[((size_t)(t * NO + o) << 8) + c] = f2bf(src[t]);
}

// ---------- conv1: h[b][ij][o] = sum_{tap,c} xp[b][pix+shift][c] * w1t[tap][o][c]; + bn1 stats ----------
__global__ __launch_bounds__(256) void k_conv1(const u16* __restrict__ xp, const u16* __restrict__ w1t,
                                               u16* __restrict__ h, float* __restrict__ s1, float* __restrict__ q1) {
    __shared__ u16 lsA[128 * 32];
    __shared__ u16 lsB[128 * 32];
    const int tid = threadIdx.x, wv = tid >> 6, lane = tid & 63;
    const int wm = wv & 1, wn = wv >> 1;
    const int bb = blockIdx.z, ij0 = blockIdx.x * 128, o0 = blockIdx.y * 128;

    f32x4 acc[4][4] = {};
    const int lr = lane >> 2, lc8 = (lane & 3) << 3;

    int apix[2], brw[2];
    u16 *sA[2], *sB[2];
#pragma unroll
    for (int u = 0; u < 2; ++u) {
        int r = (wv << 5) + (u << 4) + lr;
        int ij = ij0 + r;
        int i = ij >> 5, j = ij & 31;
        apix[u] = ((bb * PPIX + i * PW + j) << 8) + lc8;  // pad offset +6 folded into tap shift
        brw[u]  = ((o0 + r) << 8) + lc8;
        sA[u] = lsA + (r << 5) + lc8;
        sB[u] = lsB + (r << 5) + lc8;
    }
    const u16* pA0 = lsA + (((wm << 6) + (lane & 15)) << 5) + ((lane >> 4) << 3);
    const u16* pB0 = lsB + (((wn << 6) + (lane & 15)) << 5) + ((lane >> 4) << 3);

    for (int p = 0; p < 7; ++p) {
        for (int q = 0; q < 7; ++q) {
            const int toff = ((p * 2) * PW + q * 2) << 8;         // shifted pixel, stays in padded range
            const u16* wbase = w1t + ((p * 7 + q) << 16);
            for (int ci = 0; ci < 8; ++ci) {
                const int cc = ci << 5;
                uint4 va0 = *(const uint4*)(xp + apix[0] + toff + cc);
                uint4 va1 = *(const uint4*)(xp + apix[1] + toff + cc);
                uint4 vb0 = *(const uint4*)(wbase + brw[0] + cc);
                uint4 vb1 = *(const uint4*)(wbase + brw[1] + cc);
                *(uint4*)sA[0] = va0;
                *(uint4*)sA[1] = va1;
                *(uint4*)sB[0] = vb0;
                *(uint4*)sB[1] = vb1;
                __syncthreads();
                bf16x8 af[4], bv[4];
#pragma unroll
                for (int f = 0; f < 4; ++f) af[f] = *(const bf16x8*)(pA0 + (f << 9));
#pragma unroll
                for (int f = 0; f < 4; ++f) bv[f] = *(const bf16x8*)(pB0 + (f << 9));
#pragma unroll
                for (int fi = 0; fi < 4; ++fi)
#pragma unroll
                    for (int fj = 0; fj < 4; ++fj)
                        acc[fi][fj] = __builtin_amdgcn_mfma_f32_16x16x32_bf16(af[fi], bv[fj], acc[fi][fj], 0, 0, 0);
                __syncthreads();
            }
        }
    }
    // epilogue: store bf16 h + per-column (o) sum/sumsq for bn1
    const int colb = o0 + (wn << 6) + (lane & 15);
    const int rowb = ij0 + (wm << 6) + ((lane >> 4) << 2);
#pragma unroll
    for (int fj = 0; fj < 4; ++fj) {
        const int col = colb + (fj << 4);
        float s = 0.f, qq = 0.f;
#pragma unroll
        for (int fi = 0; fi < 4; ++fi) {
            const int row = rowb + (fi << 4);
#pragma unroll
            for (int v = 0; v < 4; ++v) {
                float val = acc[fi][fj][v];
                h[((size_t)((bb << 10) + row + v) << 8) + col] = f2bf(val);
                s += val; qq += val * val;
            }
        }
        s += __shfl_xor(s, 16);  s += __shfl_xor(s, 32);
        qq += __shfl_xor(qq, 16); qq += __shfl_xor(qq, 32);
        if (lane < 16) { atomicAdd(&s1[col], s); atomicAdd(&q1[col], qq); }
    }
}

// ---------- bn1 finalize: only the multiplicative part survives (additive shifts cancel in bn2) ----------
__global__ void k_bn1fin(const float* __restrict__ s1, const float* __restrict__ q1,
                         const float* __restrict__ g1, float* __restrict__ a1) {
    const int o = threadIdx.x;
    float mean = s1[o] * (1.f / 65536.f);
    float var  = fmaxf(q1[o] * (1.f / 65536.f) - mean * mean, 0.f);
    a1[o] = g1[o] * rsqrtf(var + 1e-5f);
}

// ---------- fold bn1 scale into conv2 weights: w2s[m][c] = w2[m][c] * a1[c] (bf16) ----------
__global__ __launch_bounds__(256) void k_fold2(const float* __restrict__ w2, const float* __restrict__ a1,
                                               u16* __restrict__ w2s) {
    const int m = blockIdx.x, c = threadIdx.x;
    size_t idx = ((size_t)m << 8) + c;
    w2s[idx] = f2bf(w2[idx] * a1[c]);
}

// ---------- conv2 (1x1): kb[b][ij][m] = sum_c h[b][ij][c]*w2s[m][c]; + bn2 stats ----------
__global__ __launch_bounds__(256) void k_conv2(const u16* __restrict__ h, const u16* __restrict__ w2s,
                                               u16* __restrict__ kb, float* __restrict__ s2, float* __restrict__ q2) {
    __shared__ u16 lsA[128 * 32];
    __shared__ u16 lsB[128 * 32];
    const int tid = threadIdx.x, wv = tid >> 6, lane = tid & 63;
    const int wm = wv & 1, wn = wv >> 1;
    const int bb = blockIdx.z, ij0 = blockIdx.x * 128, m0 = blockIdx.y * 128;

    f32x4 acc[4][4] = {};
    const int lr = lane >> 2, lc8 = (lane & 3) << 3;
    int arow[2], brw[2];
    u16 *sA[2], *sB[2];
#pragma unroll
    for (int u = 0; u < 2; ++u) {
        int r = (wv << 5) + (u << 4) + lr;
        arow[u] = (((bb << 10) + ij0 + r) << 8) + lc8;
        brw[u]  = ((m0 + r) << 8) + lc8;
        sA[u] = lsA + (r << 5) + lc8;
        sB[u] = lsB + (r << 5) + lc8;
    }
    const u16* pA0 = lsA + (((wm << 6) + (lane & 15)) << 5) + ((lane >> 4) << 3);
    const u16* pB0 = lsB + (((wn << 6) + (lane & 15)) << 5) + ((lane >> 4) << 3);

    for (int s = 0; s < 8; ++s) {
        const int cc = s << 5;
        uint4 va0 = *(const uint4*)(h + arow[0] + cc);
        uint4 va1 = *(const uint4*)(h + arow[1] + cc);
        uint4 vb0 = *(const uint4*)(w2s + brw[0] + cc);
        uint4 vb1 = *(const uint4*)(w2s + brw[1] + cc);
        *(uint4*)sA[0] = va0;
        *(uint4*)sA[1] = va1;
        *(uint4*)sB[0] = vb0;
        *(uint4*)sB[1] = vb1;
        __syncthreads();
        bf16x8 af[4], bv[4];
#pragma unroll
        for (int f = 0; f < 4; ++f) af[f] = *(const bf16x8*)(pA0 + (f << 9));
#pragma unroll
        for (int f = 0; f < 4; ++f) bv[f] = *(const bf16x8*)(pB0 + (f << 9));
#pragma unroll
        for (int fi = 0; fi < 4; ++fi)
#pragma unroll
            for (int fj = 0; fj < 4; ++fj)
                acc[fi][fj] = __builtin_amdgcn_mfma_f32_16x16x32_bf16(af[fi], bv[fj], acc[fi][fj], 0, 0, 0);
        __syncthreads();
    }
    const int colb = m0 + (wn << 6) + (lane & 15);
    const int rowb = ij0 + (wm << 6) + ((lane >> 4) << 2);
#pragma unroll
    for (int fj = 0; fj < 4; ++fj) {
        const int col = colb + (fj << 4);
        float s = 0.f, qq = 0.f;
#pragma unroll
        for (int fi = 0; fi < 4; ++fi) {
            const int row = rowb + (fi << 4);
#pragma unroll
            for (int v = 0; v < 4; ++v) {
                float val = acc[fi][fj][v];
                kb[((size_t)((bb << 10) + row + v) << 10) + col] = f2bf(val);
                s += val; qq += val * val;
            }
        }
        s += __shfl_xor(s, 16);  s += __shfl_xor(s, 32);
        qq += __shfl_xor(qq, 16); qq += __shfl_xor(qq, 32);
        if (lane < 16) { atomicAdd(&s2[col], s); atomicAdd(&q2[col], qq); }
    }
}

__global__ void k_bn2fin(const float* __restrict__ s2, const float* __restrict__ q2,
                         const float* __restrict__ g2, const float* __restrict__ b2,
                         float* __restrict__ a2, float* __restrict__ b2f) {
    const int m = blockIdx.x * 256 + threadIdx.x;
    float mean = s2[m] * (1.f / 65536.f);
    float var  = fmaxf(q2[m] * (1.f / 65536.f) - mean * mean, 0.f);
    float a = g2[m] * rsqrtf(var + 1e-5f);
    a2[m] = a;
    b2f[m] = b2[m] - mean * a;
}

// ---------- softmax over m (1024) per (b,ij) row, bn2 affine applied, in place ----------
__global__ __launch_bounds__(256) void k_softmax(u16* __restrict__ kb,
                                                 const float* __restrict__ a2, const float* __restrict__ b2f) {
    __shared__ float redm[4], reds[4];
    const int row = (blockIdx.y << 10) + blockIdx.x;
    u16* base = kb + ((size_t)row << 10);
    const int tid = threadIdx.x, lane = tid & 63, wv = tid >> 6;
    const int m0 = tid << 2;
    uint2 rw = *(const uint2*)(base + m0);
    float u[4];
    u[0] = __builtin_bit_cast(float, (rw.x & 0xFFFFu) << 16);
    u[1] = __builtin_bit_cast(float, rw.x & 0xFFFF0000u);
    u[2] = __builtin_bit_cast(float, (rw.y & 0xFFFFu) << 16);
    u[3] = __builtin_bit_cast(float, rw.y & 0xFFFF0000u);
#pragma unroll
    for (int i = 0; i < 4; ++i) u[i] = a2[m0 + i] * u[i] + b2f[m0 + i];
    float mx = fmaxf(fmaxf(u[0], u[1]), fmaxf(u[2], u[3]));
#pragma unroll
    for (int off = 32; off; off >>= 1) mx = fmaxf(mx, __shfl_xor(mx, off));
    if (lane == 0) redm[wv] = mx;
    __syncthreads();
    mx = fmaxf(fmaxf(redm[0], redm[1]), fmaxf(redm[2], redm[3]));
    float e[4], s = 0.f;
#pragma unroll
    for (int i = 0; i < 4; ++i) { e[i] = __expf(u[i] - mx); s += e[i]; }
#pragma unroll
    for (int off = 32; off; off >>= 1) s += __shfl_xor(s, off);
    if (lane == 0) reds[wv] = s;
    __syncthreads();
    float inv = 1.f / (reds[0] + reds[1] + reds[2] + reds[3]);
    u32 o0 = (u32)f2bf(e[0] * inv) | ((u32)f2bf(e[1] * inv) << 16);
    u32 o1 = (u32)f2bf(e[2] * inv) | ((u32)f2bf(e[3] * inv) << 16);
    *(uint2*)(base + m0) = make_uint2(o0, o1);
}

// ---------- final: out[b][ij][c] = sum_m ksm[b][ij][m] * x[b][c][m]; x is f32, out f32 ----------
__global__ __launch_bounds__(256) void k_final(const u16* __restrict__ ksm, const float* __restrict__ x,
                                               float* __restrict__ out) {
    __shared__ u16 lsA[128 * 32];
    __shared__ u16 lsB[128 * 32];
    const int tid = threadIdx.x, wv = tid >> 6, lane = tid & 63;
    const int wm = wv & 1, wn = wv >> 1;
    const int bb = blockIdx.z, ij0 = blockIdx.x * 128, c0 = blockIdx.y * 128;

    f32x4 acc[4][4] = {};
    const int lr = lane >> 2, lc8 = (lane & 3) << 3;
    int arow[2], brw[2];
    u16 *sA[2], *sB[2];
#pragma unroll
    for (int u = 0; u < 2; ++u) {
        int r = (wv << 5) + (u << 4) + lr;
        arow[u] = (((bb << 10) + ij0 + r) << 10) + lc8;
        brw[u]  = (((bb << 8) + c0 + r) << 10) + lc8;    // element offset into f32 x
        sA[u] = lsA + (r << 5) + lc8;
        sB[u] = lsB + (r << 5) + lc8;
    }
    const u16* pA0 = lsA + (((wm << 6) + (lane & 15)) << 5) + ((lane >> 4) << 3);
    const u16* pB0 = lsB + (((wn << 6) + (lane & 15)) << 5) + ((lane >> 4) << 3);

    for (int s = 0; s < 32; ++s) {
        const int cc = s << 5;
        uint4 va0 = *(const uint4*)(ksm + arow[0] + cc);
        uint4 va1 = *(const uint4*)(ksm + arow[1] + cc);
        float4 f00 = *(const float4*)(x + brw[0] + cc);
        float4 f01 = *(const float4*)(x + brw[0] + cc + 4);
        float4 f10 = *(const float4*)(x + brw[1] + cc);
        float4 f11 = *(const float4*)(x + brw[1] + cc + 4);
        uint4 vb0, vb1;
        vb0.x = (u32)f2bf(f00.x) | ((u32)f2bf(f00.y) << 16);
        vb0.y = (u32)f2bf(f00.z) | ((u32)f2bf(f00.w) << 16);
        vb0.z = (u32)f2bf(f01.x) | ((u32)f2bf(f01.y) << 16);
        vb0.w = (u32)f2bf(f01.z) | ((u32)f2bf(f01.w) << 16);
        vb1.x = (u32)f2bf(f10.x) | ((u32)f2bf(f10.y) << 16);
        vb1.y = (u32)f2bf(f10.z) | ((u32)f2bf(f10.w) << 16);
        vb1.z = (u32)f2bf(f11.x) | ((u32)f2bf(f11.y) << 16);
        vb1.w = (u32)f2bf(f11.z) | ((u32)f2bf(f11.w) << 16);
        *(uint4*)sA[0] = va0;
        *(uint4*)sA[1] = va1;
        *(uint4*)sB[0] = vb0;
        *(uint4*)sB[1] = vb1;
        __syncthreads();
        bf16x8 af[4], bv[4];
#pragma unroll
        for (int f = 0; f < 4; ++f) af[f] = *(const bf16x8*)(pA0 + (f << 9));
#pragma unroll
        for (int f = 0; f < 4; ++f) bv[f] = *(const bf16x8*)(pB0 + (f << 9));
#pragma unroll
        for (int fi = 0; fi < 4; ++fi)
#pragma unroll
            for (int fj = 0; fj < 4; ++fj)
                acc[fi][fj] = __builtin_amdgcn_mfma_f32_16x16x32_bf16(af[fi], bv[fj], acc[fi][fj], 0, 0, 0);
        __syncthreads();
    }
    const int colb = c0 + (wn << 6) + (lane & 15);
    const int rowb = ij0 + (wm << 6) + ((lane >> 4) << 2);
#pragma unroll
    for (int fi = 0; fi < 4; ++fi) {
        const int row = rowb + (fi << 4);
#pragma unroll
        for (int fj = 0; fj < 4; ++fj) {
            const int col = colb + (fj << 4);
#pragma unroll
            for (int v = 0; v < 4; ++v)
                out[((size_t)((bb << 10) + row + v) << 8) + col] = acc[fi][fj][v];
        }
    }
}

extern "C" void kernel_launch(void* const* d_in, const int* in_sizes, int n_in,
                              void* d_out, int out_size, void* d_ws, size_t ws_size,
                              hipStream_t stream) {
    const float* x  = (const float*)d_in[0];
    const float* w1 = (const float*)d_in[1];
    // d_in[2] = conv1_b : cancels through bn1
    const float* g1 = (const float*)d_in[3];
    // d_in[4] = bn1_b : cancels through bn2 (additive per-c constant -> per-m constant)
    const float* w2 = (const float*)d_in[5];
    // d_in[6] = conv2_b : cancels through bn2
    const float* g2 = (const float*)d_in[7];
    const float* b2 = (const float*)d_in[8];
    float* out = (float*)d_out;
    char* ws = (char*)d_ws;

    // ws layout (~174.3 MB): region0 shared by xp (63.4MB, dead after conv1) and kb (134MB)
    u16* xp  = (u16*)ws;
    u16* kb  = (u16*)ws;
    u16* h   = (u16*)(ws + 134217728);                 // 33.5 MB
    u16* w1t = (u16*)(ws + 134217728 + 33554432);      // 6.4 MB, shared with w2s (dead after conv1)
    u16* w2s = w1t;
    char* sm = ws + 134217728 + 33554432 + 6422528;
    float* s1  = (float*)(sm);
    float* q1  = (float*)(sm + 1024);
    float* s2  = (float*)(sm + 2048);
    float* q2  = (float*)(sm + 6144);
    float* a1  = (float*)(sm + 10240);
    float* a2  = (float*)(sm + 14336);
    float* b2f = (float*)(sm + 18432);

    hipMemsetAsync(sm, 0, 10240, stream);                             // stats accumulators
    hipMemsetAsync(xp, 0, (size_t)NB * PPIX * 256 * 2, stream);       // padded-input zeros
    k_transpose_pad<<<dim3(16, 4, NB), 256, 0, stream>>>(x, xp);
    k_w1prep<<<dim3(256), 256, 0, stream>>>(w1, w1t);
    k_conv1<<<dim3(8, 2, NB), 256, 0, stream>>>(xp, w1t, h, s1, q1);
    k_bn1fin<<<dim3(1), 256, 0, stream>>>(s1, q1, g1, a1);
    k_fold2<<<dim3(1024), 256, 0, stream>>>(w2, a1, w2s);
    k_conv2<<<dim3(8, 8, NB), 256, 0, stream>>>(h, w2s, kb, s2, q2);
    k_bn2fin<<<dim3(4), 256, 0, stream>>>(s2, q2, g2, b2, a2, b2f);
    k_softmax<<<dim3(1024, NB), 256, 0, stream>>>(kb, a2, b2f);
    k_final<<<dim3(8, 2, NB), 256, 0, stream>>>(kb, x, out);
}

// Round 4
// 942.242 us; speedup vs baseline: 1.0102x; 1.0102x over previous
//
#include <hip/hip_runtime.h>

typedef unsigned short u16;
typedef unsigned int u32;
typedef short bf16x8 __attribute__((ext_vector_type(8)));   // 8 bf16 (4 VGPRs)
typedef float f32x4 __attribute__((ext_vector_type(4)));

#define NB   64
#define NC   256
#define NO   256     // conv1 out channels
#define NM   1024    // LF*LF
#define PW   44      // padded width (32 + 2*6)
#define PPIX 1936    // 44*44

__device__ __forceinline__ u16 f2bf(float f) {
    u32 u = __builtin_bit_cast(u32, f);
    u32 r = (u + 0x7FFFu + ((u >> 16) & 1u)) >> 16;   // RNE
    return (u16)r;
}
// async global->LDS, 16B/lane; LDS dest is wave-uniform base + lane*16
__device__ __forceinline__ void ld16(const void* g, void* l) {
    __builtin_amdgcn_global_load_lds((const __attribute__((address_space(1))) u32*)g,
                                     (__attribute__((address_space(3))) u32*)l, 16, 0, 0);
}

// ---------- x[b][c][ij] (f32) -> xp[b][padded pix][c] (bf16), zero border (memset'd) ----------
__global__ __launch_bounds__(256) void k_transpose_pad(const float* __restrict__ x, u16* __restrict__ xp) {
    __shared__ u16 tile[64 * 65];
    const int b = blockIdx.z, ij0 = blockIdx.x * 64, c0 = blockIdx.y * 64;
    const int tid = threadIdx.x;
#pragma unroll
    for (int it = 0; it < 16; ++it) {
        int idx = it * 256 + tid;
        int cr = idx >> 6, ijr = idx & 63;
        tile[ijr * 65 + cr] = f2bf(x[((size_t)(b * NC + c0 + cr) << 10) + ij0 + ijr]);
    }
    __syncthreads();
#pragma unroll
    for (int it = 0; it < 16; ++it) {
        int idx = it * 256 + tid;
        int ijr = idx >> 6, cr = idx & 63;
        int pix = ij0 + ijr;
        int i = pix >> 5, j = pix & 31;
        int prow = (i + 6) * PW + (j + 6);
        xp[((size_t)(b * PPIX + prow) << 8) + c0 + cr] = tile[ijr * 65 + cr];
    }
}

// ---------- conv1_w (O,C,7,7) f32 -> w1t[tap][o][c] bf16 ----------
__global__ __launch_bounds__(256) void k_w1prep(const float* __restrict__ w1, u16* __restrict__ w1t) {
    const int o = blockIdx.x, c = threadIdx.x;
    const float* src = w1 + ((size_t)(o * NC + c)) * 49;
#pragma unroll
    for (int t = 0; t < 49; ++t)
        w1t[((size_t)(t * NO + o) << 8) + c] = f2bf(src[t]);
}

// ---------- conv1: h[b][ij][o] = sum_{tap,c} xp[b][pix+shift][c] * w1t[tap][o][c]; + bn1 stats ----------
__global__ __launch_bounds__(256) void k_conv1(const u16* __restrict__ xp, const u16* __restrict__ w1t,
                                               u16* __restrict__ h, float* __restrict__ s1, float* __restrict__ q1) {
    __shared__ u16 lsA[128 * 32];
    __shared__ u16 lsB[128 * 32];
    const int tid = threadIdx.x, wv = tid >> 6, lane = tid & 63;
    const int wm = wv & 1, wn = wv >> 1;
    const int bb = blockIdx.z, ij0 = blockIdx.x * 128, o0 = blockIdx.y * 128;

    f32x4 acc[4][4] = {};
    const int lr = lane >> 2, lc8 = (lane & 3) << 3;

    int apix[2], brw[2];
    u16 *dA[2], *dB[2];
#pragma unroll
    for (int u = 0; u < 2; ++u) {
        int r = (wv << 5) + (u << 4) + lr;
        int ij = ij0 + r;
        int i = ij >> 5, j = ij & 31;
        apix[u] = ((bb * PPIX + i * PW + j) << 8) + lc8;  // pad offset +6 folded into tap shift
        brw[u]  = ((o0 + r) << 8) + lc8;
        dA[u] = lsA + (((wv << 5) + (u << 4)) << 5);      // wave-uniform LDS base
        dB[u] = lsB + (((wv << 5) + (u << 4)) << 5);
    }
    const u16* pA0 = lsA + (((wm << 6) + (lane & 15)) << 5) + ((lane >> 4) << 3);
    const u16* pB0 = lsB + (((wn << 6) + (lane & 15)) << 5) + ((lane >> 4) << 3);

    for (int p = 0; p < 7; ++p) {
        for (int q = 0; q < 7; ++q) {
            const int toff = ((p * 2) * PW + q * 2) << 8;         // shifted pixel, stays in padded range
            const u16* wbase = w1t + ((p * 7 + q) << 16);
            for (int ci = 0; ci < 8; ++ci) {
                const int cc = ci << 5;
#pragma unroll
                for (int u = 0; u < 2; ++u) {
                    ld16(xp + apix[u] + toff + cc, dA[u]);
                    ld16(wbase + brw[u] + cc, dB[u]);
                }
                __syncthreads();
                bf16x8 af[4], bv[4];
#pragma unroll
                for (int f = 0; f < 4; ++f) af[f] = *(const bf16x8*)(pA0 + (f << 9));
#pragma unroll
                for (int f = 0; f < 4; ++f) bv[f] = *(const bf16x8*)(pB0 + (f << 9));
#pragma unroll
                for (int fi = 0; fi < 4; ++fi)
#pragma unroll
                    for (int fj = 0; fj < 4; ++fj)
                        acc[fi][fj] = __builtin_amdgcn_mfma_f32_16x16x32_bf16(af[fi], bv[fj], acc[fi][fj], 0, 0, 0);
                __syncthreads();
            }
        }
    }
    // epilogue: store bf16 h + per-column (o) sum/sumsq for bn1
    const int colb = o0 + (wn << 6) + (lane & 15);
    const int rowb = ij0 + (wm << 6) + ((lane >> 4) << 2);
#pragma unroll
    for (int fj = 0; fj < 4; ++fj) {
        const int col = colb + (fj << 4);
        float s = 0.f, qq = 0.f;
#pragma unroll
        for (int fi = 0; fi < 4; ++fi) {
            const int row = rowb + (fi << 4);
#pragma unroll
            for (int v = 0; v < 4; ++v) {
                float val = acc[fi][fj][v];
                h[((size_t)((bb << 10) + row + v) << 8) + col] = f2bf(val);
                s += val; qq += val * val;
            }
        }
        s += __shfl_xor(s, 16);  s += __shfl_xor(s, 32);
        qq += __shfl_xor(qq, 16); qq += __shfl_xor(qq, 32);
        if (lane < 16) { atomicAdd(&s1[col], s); atomicAdd(&q1[col], qq); }
    }
}

// ---------- bn1 finalize: only the multiplicative part survives (additive shifts cancel in bn2) ----------
__global__ void k_bn1fin(const float* __restrict__ s1, const float* __restrict__ q1,
                         const float* __restrict__ g1, float* __restrict__ a1) {
    const int o = threadIdx.x;
    float mean = s1[o] * (1.f / 65536.f);
    float var  = fmaxf(q1[o] * (1.f / 65536.f) - mean * mean, 0.f);
    a1[o] = g1[o] * rsqrtf(var + 1e-5f);
}

// ---------- fold bn1 scale into conv2 weights: w2s[m][c] = w2[m][c] * a1[c] (bf16) ----------
__global__ __launch_bounds__(256) void k_fold2(const float* __restrict__ w2, const float* __restrict__ a1,
                                               u16* __restrict__ w2s) {
    const int m = blockIdx.x, c = threadIdx.x;
    size_t idx = ((size_t)m << 8) + c;
    w2s[idx] = f2bf(w2[idx] * a1[c]);
}

// ---------- conv2 (1x1): kb[b][ij][m] = sum_c h[b][ij][c]*w2s[m][c]; + bn2 stats ----------
__global__ __launch_bounds__(256) void k_conv2(const u16* __restrict__ h, const u16* __restrict__ w2s,
                                               u16* __restrict__ kb, float* __restrict__ s2, float* __restrict__ q2) {
    __shared__ u16 lsA[128 * 32];
    __shared__ u16 lsB[128 * 32];
    const int tid = threadIdx.x, wv = tid >> 6, lane = tid & 63;
    const int wm = wv & 1, wn = wv >> 1;
    const int bb = blockIdx.z, ij0 = blockIdx.x * 128, m0 = blockIdx.y * 128;

    f32x4 acc[4][4] = {};
    const int lr = lane >> 2, lc8 = (lane & 3) << 3;
    int arow[2], brw[2];
    u16 *dA[2], *dB[2];
#pragma unroll
    for (int u = 0; u < 2; ++u) {
        int r = (wv << 5) + (u << 4) + lr;
        arow[u] = (((bb << 10) + ij0 + r) << 8) + lc8;
        brw[u]  = ((m0 + r) << 8) + lc8;
        dA[u] = lsA + (((wv << 5) + (u << 4)) << 5);
        dB[u] = lsB + (((wv << 5) + (u << 4)) << 5);
    }
    const u16* pA0 = lsA + (((wm << 6) + (lane & 15)) << 5) + ((lane >> 4) << 3);
    const u16* pB0 = lsB + (((wn << 6) + (lane & 15)) << 5) + ((lane >> 4) << 3);

    for (int s = 0; s < 8; ++s) {
        const int cc = s << 5;
#pragma unroll
        for (int u = 0; u < 2; ++u) {
            ld16(h + arow[u] + cc, dA[u]);
            ld16(w2s + brw[u] + cc, dB[u]);
        }
        __syncthreads();
        bf16x8 af[4], bv[4];
#pragma unroll
        for (int f = 0; f < 4; ++f) af[f] = *(const bf16x8*)(pA0 + (f << 9));
#pragma unroll
        for (int f = 0; f < 4; ++f) bv[f] = *(const bf16x8*)(pB0 + (f << 9));
#pragma unroll
        for (int fi = 0; fi < 4; ++fi)
#pragma unroll
            for (int fj = 0; fj < 4; ++fj)
                acc[fi][fj] = __builtin_amdgcn_mfma_f32_16x16x32_bf16(af[fi], bv[fj], acc[fi][fj], 0, 0, 0);
        __syncthreads();
    }
    const int colb = m0 + (wn << 6) + (lane & 15);
    const int rowb = ij0 + (wm << 6) + ((lane >> 4) << 2);
#pragma unroll
    for (int fj = 0; fj < 4; ++fj) {
        const int col = colb + (fj << 4);
        float s = 0.f, qq = 0.f;
#pragma unroll
        for (int fi = 0; fi < 4; ++fi) {
            const int row = rowb + (fi << 4);
#pragma unroll
            for (int v = 0; v < 4; ++v) {
                float val = acc[fi][fj][v];
                kb[((size_t)((bb << 10) + row + v) << 10) + col] = f2bf(val);
                s += val; qq += val * val;
            }
        }
        s += __shfl_xor(s, 16);  s += __shfl_xor(s, 32);
        qq += __shfl_xor(qq, 16); qq += __shfl_xor(qq, 32);
        if (lane < 16) { atomicAdd(&s2[col], s); atomicAdd(&q2[col], qq); }
    }
}

__global__ void k_bn2fin(const float* __restrict__ s2, const float* __restrict__ q2,
                         const float* __restrict__ g2, const float* __restrict__ b2,
                         float* __restrict__ a2, float* __restrict__ b2f) {
    const int m = blockIdx.x * 256 + threadIdx.x;
    float mean = s2[m] * (1.f / 65536.f);
    float var  = fmaxf(q2[m] * (1.f / 65536.f) - mean * mean, 0.f);
    float a = g2[m] * rsqrtf(var + 1e-5f);
    a2[m] = a;
    b2f[m] = b2[m] - mean * a;
}

// ---------- softmax over m (1024) per (b,ij) row, bn2 affine applied, in place ----------
__global__ __launch_bounds__(256) void k_softmax(u16* __restrict__ kb,
                                                 const float* __restrict__ a2, const float* __restrict__ b2f) {
    __shared__ float redm[4], reds[4];
    const int row = (blockIdx.y << 10) + blockIdx.x;
    u16* base = kb + ((size_t)row << 10);
    const int tid = threadIdx.x, lane = tid & 63, wv = tid >> 6;
    const int m0 = tid << 2;
    uint2 rw = *(const uint2*)(base + m0);
    float u[4];
    u[0] = __builtin_bit_cast(float, (rw.x & 0xFFFFu) << 16);
    u[1] = __builtin_bit_cast(float, rw.x & 0xFFFF0000u);
    u[2] = __builtin_bit_cast(float, (rw.y & 0xFFFFu) << 16);
    u[3] = __builtin_bit_cast(float, rw.y & 0xFFFF0000u);
#pragma unroll
    for (int i = 0; i < 4; ++i) u[i] = a2[m0 + i] * u[i] + b2f[m0 + i];
    float mx = fmaxf(fmaxf(u[0], u[1]), fmaxf(u[2], u[3]));
#pragma unroll
    for (int off = 32; off; off >>= 1) mx = fmaxf(mx, __shfl_xor(mx, off));
    if (lane == 0) redm[wv] = mx;
    __syncthreads();
    mx = fmaxf(fmaxf(redm[0], redm[1]), fmaxf(redm[2], redm[3]));
    float e[4], s = 0.f;
#pragma unroll
    for (int i = 0; i < 4; ++i) { e[i] = __expf(u[i] - mx); s += e[i]; }
#pragma unroll
    for (int off = 32; off; off >>= 1) s += __shfl_xor(s, off);
    if (lane == 0) reds[wv] = s;
    __syncthreads();
    float inv = 1.f / (reds[0] + reds[1] + reds[2] + reds[3]);
    u32 o0 = (u32)f2bf(e[0] * inv) | ((u32)f2bf(e[1] * inv) << 16);
    u32 o1 = (u32)f2bf(e[2] * inv) | ((u32)f2bf(e[3] * inv) << 16);
    *(uint2*)(base + m0) = make_uint2(o0, o1);
}

// ---------- final: out[b][ij][c] = sum_m ksm[b][ij][m] * x[b][c][m]; x is f32, out f32 ----------
__global__ __launch_bounds__(256) void k_final(const u16* __restrict__ ksm, const float* __restrict__ x,
                                               float* __restrict__ out) {
    __shared__ u16 lsA[128 * 32];
    __shared__ u16 lsB[128 * 32];
    const int tid = threadIdx.x, wv = tid >> 6, lane = tid & 63;
    const int wm = wv & 1, wn = wv >> 1;
    const int bb = blockIdx.z, ij0 = blockIdx.x * 128, c0 = blockIdx.y * 128;

    f32x4 acc[4][4] = {};
    const int lr = lane >> 2, lc8 = (lane & 3) << 3;
    int arow[2], brw[2];
    u16 *dA[2], *sB[2];
#pragma unroll
    for (int u = 0; u < 2; ++u) {
        int r = (wv << 5) + (u << 4) + lr;
        arow[u] = (((bb << 10) + ij0 + r) << 10) + lc8;
        brw[u]  = (((bb << 8) + c0 + r) << 10) + lc8;    // element offset into f32 x
        dA[u] = lsA + (((wv << 5) + (u << 4)) << 5);     // wave-uniform, glld
        sB[u] = lsB + (((wv << 5) + (u << 4) + lr) << 5) + lc8;  // per-lane store slot
    }
    const u16* pA0 = lsA + (((wm << 6) + (lane & 15)) << 5) + ((lane >> 4) << 3);
    const u16* pB0 = lsB + (((wn << 6) + (lane & 15)) << 5) + ((lane >> 4) << 3);

    for (int s = 0; s < 32; ++s) {
        const int cc = s << 5;
#pragma unroll
        for (int u = 0; u < 2; ++u) ld16(ksm + arow[u] + cc, dA[u]);
        float4 f00 = *(const float4*)(x + brw[0] + cc);
        float4 f01 = *(const float4*)(x + brw[0] + cc + 4);
        float4 f10 = *(const float4*)(x + brw[1] + cc);
        float4 f11 = *(const float4*)(x + brw[1] + cc + 4);
        uint4 vb0, vb1;
        vb0.x = (u32)f2bf(f00.x) | ((u32)f2bf(f00.y) << 16);
        vb0.y = (u32)f2bf(f00.z) | ((u32)f2bf(f00.w) << 16);
        vb0.z = (u32)f2bf(f01.x) | ((u32)f2bf(f01.y) << 16);
        vb0.w = (u32)f2bf(f01.z) | ((u32)f2bf(f01.w) << 16);
        vb1.x = (u32)f2bf(f10.x) | ((u32)f2bf(f10.y) << 16);
        vb1.y = (u32)f2bf(f10.z) | ((u32)f2bf(f10.w) << 16);
        vb1.z = (u32)f2bf(f11.x) | ((u32)f2bf(f11.y) << 16);
        vb1.w = (u32)f2bf(f11.z) | ((u32)f2bf(f11.w) << 16);
        *(uint4*)sB[0] = vb0;
        *(uint4*)sB[1] = vb1;
        __syncthreads();
        bf16x8 af[4], bv[4];
#pragma unroll
        for (int f = 0; f < 4; ++f) af[f] = *(const bf16x8*)(pA0 + (f << 9));
#pragma unroll
        for (int f = 0; f < 4; ++f) bv[f] = *(const bf16x8*)(pB0 + (f << 9));
#pragma unroll
        for (int fi = 0; fi < 4; ++fi)
#pragma unroll
            for (int fj = 0; fj < 4; ++fj)
                acc[fi][fj] = __builtin_amdgcn_mfma_f32_16x16x32_bf16(af[fi], bv[fj], acc[fi][fj], 0, 0, 0);
        __syncthreads();
    }
    const int colb = c0 + (wn << 6) + (lane & 15);
    const int rowb = ij0 + (wm << 6) + ((lane >> 4) << 2);
#pragma unroll
    for (int fi = 0; fi < 4; ++fi) {
        const int row = rowb + (fi << 4);
#pragma unroll
        for (int fj = 0; fj < 4; ++fj) {
            const int col = colb + (fj << 4);
#pragma unroll
            for (int v = 0; v < 4; ++v)
                out[((size_t)((bb << 10) + row + v) << 8) + col] = acc[fi][fj][v];
        }
    }
}

extern "C" void kernel_launch(void* const* d_in, const int* in_sizes, int n_in,
                              void* d_out, int out_size, void* d_ws, size_t ws_size,
                              hipStream_t stream) {
    const float* x  = (const float*)d_in[0];
    const float* w1 = (const float*)d_in[1];
    // d_in[2] = conv1_b : cancels through bn1
    const float* g1 = (const float*)d_in[3];
    // d_in[4] = bn1_b : cancels through bn2 (additive per-c constant -> per-m constant)
    const float* w2 = (const float*)d_in[5];
    // d_in[6] = conv2_b : cancels through bn2
    const float* g2 = (const float*)d_in[7];
    const float* b2 = (const float*)d_in[8];
    float* out = (float*)d_out;
    char* ws = (char*)d_ws;

    // ws layout (~174.3 MB): region0 shared by xp (63.4MB, dead after conv1) and kb (134MB)
    u16* xp  = (u16*)ws;
    u16* kb  = (u16*)ws;
    u16* h   = (u16*)(ws + 134217728);                 // 33.5 MB
    u16* w1t = (u16*)(ws + 134217728 + 33554432);      // 6.4 MB, shared with w2s (dead after conv1)
    u16* w2s = w1t;
    char* sm = ws + 134217728 + 33554432 + 6422528;
    float* s1  = (float*)(sm);
    float* q1  = (float*)(sm + 1024);
    float* s2  = (float*)(sm + 2048);
    float* q2  = (float*)(sm + 6144);
    float* a1  = (float*)(sm + 10240);
    float* a2  = (float*)(sm + 14336);
    float* b2f = (float*)(sm + 18432);

    hipMemsetAsync(sm, 0, 10240, stream);                             // stats accumulators
    hipMemsetAsync(xp, 0, (size_t)NB * PPIX * 256 * 2, stream);       // padded-input zeros
    k_transpose_pad<<<dim3(16, 4, NB), 256, 0, stream>>>(x, xp);
    k_w1prep<<<dim3(256), 256, 0, stream>>>(w1, w1t);
    k_conv1<<<dim3(8, 2, NB), 256, 0, stream>>>(xp, w1t, h, s1, q1);
    k_bn1fin<<<dim3(1), 256, 0, stream>>>(s1, q1, g1, a1);
    k_fold2<<<dim3(1024), 256, 0, stream>>>(w2, a1, w2s);
    k_conv2<<<dim3(8, 8, NB), 256, 0, stream>>>(h, w2s, kb, s2, q2);
    k_bn2fin<<<dim3(4), 256, 0, stream>>>(s2, q2, g2, b2, a2, b2f);
    k_softmax<<<dim3(1024, NB), 256, 0, stream>>>(kb, a2, b2f);
    k_final<<<dim3(8, 2, NB), 256, 0, stream>>>(kb, x, out);
}

// Round 5
// 900.012 us; speedup vs baseline: 1.0576x; 1.0469x over previous
//
#include <hip/hip_runtime.h>

typedef unsigned short u16;
typedef unsigned int u32;
typedef short bf16x8 __attribute__((ext_vector_type(8)));   // 8 bf16 (4 VGPRs)
typedef float f32x4 __attribute__((ext_vector_type(4)));

#define NB   64
#define NC   256
#define NO   256     // conv1 out channels
#define NM   1024    // LF*LF
#define PW   44      // padded width (32 + 2*6)
#define PPIX 1936    // 44*44

__device__ __forceinline__ u16 f2bf(float f) {
    u32 u = __builtin_bit_cast(u32, f);
    u32 r = (u + 0x7FFFu + ((u >> 16) & 1u)) >> 16;   // RNE
    return (u16)r;
}
// async global->LDS, 16B/lane; LDS dest is wave-uniform base + lane*16
__device__ __forceinline__ void ld16(const void* g, void* l) {
    __builtin_amdgcn_global_load_lds((const __attribute__((address_space(1))) u32*)g,
                                     (__attribute__((address_space(3))) u32*)l, 16, 0, 0);
}

// ---------- x[b][c][ij] (f32) -> xp[b][padded pix][c] (bf16), zero border (memset'd) ----------
__global__ __launch_bounds__(256) void k_transpose_pad(const float* __restrict__ x, u16* __restrict__ xp) {
    __shared__ u16 tile[64 * 65];
    const int b = blockIdx.z, ij0 = blockIdx.x * 64, c0 = blockIdx.y * 64;
    const int tid = threadIdx.x;
#pragma unroll
    for (int it = 0; it < 16; ++it) {
        int idx = it * 256 + tid;
        int cr = idx >> 6, ijr = idx & 63;
        tile[ijr * 65 + cr] = f2bf(x[((size_t)(b * NC + c0 + cr) << 10) + ij0 + ijr]);
    }
    __syncthreads();
#pragma unroll
    for (int it = 0; it < 16; ++it) {
        int idx = it * 256 + tid;
        int ijr = idx >> 6, cr = idx & 63;
        int pix = ij0 + ijr;
        int i = pix >> 5, j = pix & 31;
        int prow = (i + 6) * PW + (j + 6);
        xp[((size_t)(b * PPIX + prow) << 8) + c0 + cr] = tile[ijr * 65 + cr];
    }
}

// ---------- conv1_w (O,C,7,7) f32 -> w1t[tap][o][c] bf16 ----------
__global__ __launch_bounds__(256) void k_w1prep(const float* __restrict__ w1, u16* __restrict__ w1t) {
    const int o = blockIdx.x, c = threadIdx.x;
    const float* src = w1 + ((size_t)(o * NC + c)) * 49;
#pragma unroll
    for (int t = 0; t < 49; ++t)
        w1t[((size_t)(t * NO + o) << 8) + c] = f2bf(src[t]);
}

// ---------- conv1: h[b][ij][o] = sum_{tap,c} xp[..][c] * w1t[tap][o][c]; + bn1 stats ----------
// Block tile 256(M=pixels) x 128(N=outch), BK=64 staged as 2 chunks of 32.
// 4 waves as 2x2, each wave 128x64 (acc = 8x4 f32x4 = 128 regs).
__global__ __launch_bounds__(256, 2) void k_conv1(const u16* __restrict__ xp, const u16* __restrict__ w1t,
                                                  u16* __restrict__ h, float* __restrict__ s1, float* __restrict__ q1) {
    __shared__ u16 lsA[2 * 256 * 32];   // [kk][row 256][32]
    __shared__ u16 lsB[2 * 128 * 32];   // [kk][orow 128][32]
    const int tid = threadIdx.x, wv = tid >> 6, lane = tid & 63;
    const int wm = wv & 1, wn = wv >> 1;
    const int bb = blockIdx.z, ij0 = blockIdx.x * 256, o0 = blockIdx.y * 128;

    f32x4 acc[8][4] = {};
    const int lq = lane >> 2, lc8 = (lane & 3) << 3;   // staging: row-in-16 = lane>>2, col = (lane&3)*8

    // A staging: 8 calls/wave/stage (t = kk*4 + tq), rows = wv*64 + tq*16 + lq
    int apix[8];
    u16* dA[8];
#pragma unroll
    for (int t = 0; t < 8; ++t) {
        int kk = t >> 2, tq = t & 3;
        int gr = ij0 + (wv << 6) + (tq << 4) + lq;       // global pixel row of A
        int i = gr >> 5, j = gr & 31;
        apix[t] = ((bb * PPIX + i * PW + j) << 8) + (kk << 5) + lc8;
        dA[t] = lsA + (kk << 13) + (((wv << 6) + (tq << 4)) << 5);
    }
    // B staging: 4 calls/wave/stage (u2 = kk*2 + u), o-rows = wv*32 + u*16 + lq
    int brw[4];
    u16* dB[4];
#pragma unroll
    for (int u2 = 0; u2 < 4; ++u2) {
        int kk = u2 >> 1, u = u2 & 1;
        brw[u2] = ((o0 + (wv << 5) + (u << 4) + lq) << 8) + (kk << 5) + lc8;
        dB[u2] = lsB + (kk << 12) + (((wv << 5) + (u << 4)) << 5);
    }
    // fragment read pointers
    const u16* pA0 = lsA + (((wm << 7) + (lane & 15)) << 5) + ((lane >> 4) << 3);
    const u16* pB0 = lsB + (((wn << 6) + (lane & 15)) << 5) + ((lane >> 4) << 3);

    for (int p = 0; p < 7; ++p) {
        for (int q = 0; q < 7; ++q) {
            const int toff = ((p * 2) * PW + q * 2) << 8;         // tap shift in padded image
            const u16* wbase = w1t + ((p * 7 + q) << 16);
            for (int ci = 0; ci < 4; ++ci) {
                const int coff = ci << 6;                          // 64-channel chunk
#pragma unroll
                for (int t = 0; t < 8; ++t) ld16(xp + apix[t] + toff + coff, dA[t]);
#pragma unroll
                for (int u2 = 0; u2 < 4; ++u2) ld16(wbase + brw[u2] + coff, dB[u2]);
                __syncthreads();
#pragma unroll
                for (int kk = 0; kk < 2; ++kk) {
                    bf16x8 bv[4];
#pragma unroll
                    for (int fj = 0; fj < 4; ++fj)
                        bv[fj] = *(const bf16x8*)(pB0 + (kk << 12) + (fj << 9));
#pragma unroll
                    for (int fi = 0; fi < 8; ++fi) {
                        bf16x8 af = *(const bf16x8*)(pA0 + (kk << 13) + (fi << 9));
#pragma unroll
                        for (int fj = 0; fj < 4; ++fj)
                            acc[fi][fj] = __builtin_amdgcn_mfma_f32_16x16x32_bf16(af, bv[fj], acc[fi][fj], 0, 0, 0);
                    }
                }
                __syncthreads();
            }
        }
    }
    // epilogue: store bf16 h + per-column (o) sum/sumsq for bn1
    const int colb = o0 + (wn << 6) + (lane & 15);
    const int rowb = ij0 + (wm << 7) + ((lane >> 4) << 2);
#pragma unroll
    for (int fj = 0; fj < 4; ++fj) {
        const int col = colb + (fj << 4);
        float s = 0.f, qq = 0.f;
#pragma unroll
        for (int fi = 0; fi < 8; ++fi) {
            const int row = rowb + (fi << 4);
#pragma unroll
            for (int v = 0; v < 4; ++v) {
                float val = acc[fi][fj][v];
                h[((size_t)((bb << 10) + row + v) << 8) + col] = f2bf(val);
                s += val; qq += val * val;
            }
        }
        s += __shfl_xor(s, 16);  s += __shfl_xor(s, 32);
        qq += __shfl_xor(qq, 16); qq += __shfl_xor(qq, 32);
        if (lane < 16) { atomicAdd(&s1[col], s); atomicAdd(&q1[col], qq); }
    }
}

// ---------- bn1 finalize: only the multiplicative part survives (additive shifts cancel in bn2) ----------
__global__ void k_bn1fin(const float* __restrict__ s1, const float* __restrict__ q1,
                         const float* __restrict__ g1, float* __restrict__ a1) {
    const int o = threadIdx.x;
    float mean = s1[o] * (1.f / 65536.f);
    float var  = fmaxf(q1[o] * (1.f / 65536.f) - mean * mean, 0.f);
    a1[o] = g1[o] * rsqrtf(var + 1e-5f);
}

// ---------- fold bn1 scale into conv2 weights: w2s[m][c] = w2[m][c] * a1[c] (bf16) ----------
__global__ __launch_bounds__(256) void k_fold2(const float* __restrict__ w2, const float* __restrict__ a1,
                                               u16* __restrict__ w2s) {
    const int m = blockIdx.x, c = threadIdx.x;
    size_t idx = ((size_t)m << 8) + c;
    w2s[idx] = f2bf(w2[idx] * a1[c]);
}

// ---------- conv2 (1x1): kb[b][ij][m] = sum_c h[b][ij][c]*w2s[m][c]; + bn2 stats ----------
__global__ __launch_bounds__(256) void k_conv2(const u16* __restrict__ h, const u16* __restrict__ w2s,
                                               u16* __restrict__ kb, float* __restrict__ s2, float* __restrict__ q2) {
    __shared__ u16 lsA[128 * 32];
    __shared__ u16 lsB[128 * 32];
    const int tid = threadIdx.x, wv = tid >> 6, lane = tid & 63;
    const int wm = wv & 1, wn = wv >> 1;
    const int bb = blockIdx.z, ij0 = blockIdx.x * 128, m0 = blockIdx.y * 128;

    f32x4 acc[4][4] = {};
    const int lr = lane >> 2, lc8 = (lane & 3) << 3;
    int arow[2], brw[2];
    u16 *dA[2], *dB[2];
#pragma unroll
    for (int u = 0; u < 2; ++u) {
        int r = (wv << 5) + (u << 4) + lr;
        arow[u] = (((bb << 10) + ij0 + r) << 8) + lc8;
        brw[u]  = ((m0 + r) << 8) + lc8;
        dA[u] = lsA + (((wv << 5) + (u << 4)) << 5);
        dB[u] = lsB + (((wv << 5) + (u << 4)) << 5);
    }
    const u16* pA0 = lsA + (((wm << 6) + (lane & 15)) << 5) + ((lane >> 4) << 3);
    const u16* pB0 = lsB + (((wn << 6) + (lane & 15)) << 5) + ((lane >> 4) << 3);

    for (int s = 0; s < 8; ++s) {
        const int cc = s << 5;
#pragma unroll
        for (int u = 0; u < 2; ++u) {
            ld16(h + arow[u] + cc, dA[u]);
            ld16(w2s + brw[u] + cc, dB[u]);
        }
        __syncthreads();
        bf16x8 af[4], bv[4];
#pragma unroll
        for (int f = 0; f < 4; ++f) af[f] = *(const bf16x8*)(pA0 + (f << 9));
#pragma unroll
        for (int f = 0; f < 4; ++f) bv[f] = *(const bf16x8*)(pB0 + (f << 9));
#pragma unroll
        for (int fi = 0; fi < 4; ++fi)
#pragma unroll
            for (int fj = 0; fj < 4; ++fj)
                acc[fi][fj] = __builtin_amdgcn_mfma_f32_16x16x32_bf16(af[fi], bv[fj], acc[fi][fj], 0, 0, 0);
        __syncthreads();
    }
    const int colb = m0 + (wn << 6) + (lane & 15);
    const int rowb = ij0 + (wm << 6) + ((lane >> 4) << 2);
#pragma unroll
    for (int fj = 0; fj < 4; ++fj) {
        const int col = colb + (fj << 4);
        float s = 0.f, qq = 0.f;
#pragma unroll
        for (int fi = 0; fi < 4; ++fi) {
            const int row = rowb + (fi << 4);
#pragma unroll
            for (int v = 0; v < 4; ++v) {
                float val = acc[fi][fj][v];
                kb[((size_t)((bb << 10) + row + v) << 10) + col] = f2bf(val);
                s += val; qq += val * val;
            }
        }
        s += __shfl_xor(s, 16);  s += __shfl_xor(s, 32);
        qq += __shfl_xor(qq, 16); qq += __shfl_xor(qq, 32);
        if (lane < 16) { atomicAdd(&s2[col], s); atomicAdd(&q2[col], qq); }
    }
}

__global__ void k_bn2fin(const float* __restrict__ s2, const float* __restrict__ q2,
                         const float* __restrict__ g2, const float* __restrict__ b2,
                         float* __restrict__ a2, float* __restrict__ b2f) {
    const int m = blockIdx.x * 256 + threadIdx.x;
    float mean = s2[m] * (1.f / 65536.f);
    float var  = fmaxf(q2[m] * (1.f / 65536.f) - mean * mean, 0.f);
    float a = g2[m] * rsqrtf(var + 1e-5f);
    a2[m] = a;
    b2f[m] = b2[m] - mean * a;
}

// ---------- softmax over m (1024) per (b,ij) row, bn2 affine applied, in place ----------
__global__ __launch_bounds__(256) void k_softmax(u16* __restrict__ kb,
                                                 const float* __restrict__ a2, const float* __restrict__ b2f) {
    __shared__ float redm[4], reds[4];
    const int row = (blockIdx.y << 10) + blockIdx.x;
    u16* base = kb + ((size_t)row << 10);
    const int tid = threadIdx.x, lane = tid & 63, wv = tid >> 6;
    const int m0 = tid << 2;
    uint2 rw = *(const uint2*)(base + m0);
    float u[4];
    u[0] = __builtin_bit_cast(float, (rw.x & 0xFFFFu) << 16);
    u[1] = __builtin_bit_cast(float, rw.x & 0xFFFF0000u);
    u[2] = __builtin_bit_cast(float, (rw.y & 0xFFFFu) << 16);
    u[3] = __builtin_bit_cast(float, rw.y & 0xFFFF0000u);
#pragma unroll
    for (int i = 0; i < 4; ++i) u[i] = a2[m0 + i] * u[i] + b2f[m0 + i];
    float mx = fmaxf(fmaxf(u[0], u[1]), fmaxf(u[2], u[3]));
#pragma unroll
    for (int off = 32; off; off >>= 1) mx = fmaxf(mx, __shfl_xor(mx, off));
    if (lane == 0) redm[wv] = mx;
    __syncthreads();
    mx = fmaxf(fmaxf(redm[0], redm[1]), fmaxf(redm[2], redm[3]));
    float e[4], s = 0.f;
#pragma unroll
    for (int i = 0; i < 4; ++i) { e[i] = __expf(u[i] - mx); s += e[i]; }
#pragma unroll
    for (int off = 32; off; off >>= 1) s += __shfl_xor(s, off);
    if (lane == 0) reds[wv] = s;
    __syncthreads();
    float inv = 1.f / (reds[0] + reds[1] + reds[2] + reds[3]);
    u32 o0 = (u32)f2bf(e[0] * inv) | ((u32)f2bf(e[1] * inv) << 16);
    u32 o1 = (u32)f2bf(e[2] * inv) | ((u32)f2bf(e[3] * inv) << 16);
    *(uint2*)(base + m0) = make_uint2(o0, o1);
}

// ---------- final: out[b][ij][c] = sum_m ksm[b][ij][m] * x[b][c][m]; x is f32, out f32 ----------
__global__ __launch_bounds__(256) void k_final(const u16* __restrict__ ksm, const float* __restrict__ x,
                                               float* __restrict__ out) {
    __shared__ u16 lsA[128 * 32];
    __shared__ u16 lsB[128 * 32];
    const int tid = threadIdx.x, wv = tid >> 6, lane = tid & 63;
    const int wm = wv & 1, wn = wv >> 1;
    const int bb = blockIdx.z, ij0 = blockIdx.x * 128, c0 = blockIdx.y * 128;

    f32x4 acc[4][4] = {};
    const int lr = lane >> 2, lc8 = (lane & 3) << 3;
    int arow[2], brw[2];
    u16 *dA[2], *sB[2];
#pragma unroll
    for (int u = 0; u < 2; ++u) {
        int r = (wv << 5) + (u << 4) + lr;
        arow[u] = (((bb << 10) + ij0 + r) << 10) + lc8;
        brw[u]  = (((bb << 8) + c0 + r) << 10) + lc8;    // element offset into f32 x
        dA[u] = lsA + (((wv << 5) + (u << 4)) << 5);     // wave-uniform, glld
        sB[u] = lsB + (((wv << 5) + (u << 4) + lr) << 5) + lc8;  // per-lane store slot
    }
    const u16* pA0 = lsA + (((wm << 6) + (lane & 15)) << 5) + ((lane >> 4) << 3);
    const u16* pB0 = lsB + (((wn << 6) + (lane & 15)) << 5) + ((lane >> 4) << 3);

    for (int s = 0; s < 32; ++s) {
        const int cc = s << 5;
#pragma unroll
        for (int u = 0; u < 2; ++u) ld16(ksm + arow[u] + cc, dA[u]);
        float4 f00 = *(const float4*)(x + brw[0] + cc);
        float4 f01 = *(const float4*)(x + brw[0] + cc + 4);
        float4 f10 = *(const float4*)(x + brw[1] + cc);
        float4 f11 = *(const float4*)(x + brw[1] + cc + 4);
        uint4 vb0, vb1;
        vb0.x = (u32)f2bf(f00.x) | ((u32)f2bf(f00.y) << 16);
        vb0.y = (u32)f2bf(f00.z) | ((u32)f2bf(f00.w) << 16);
        vb0.z = (u32)f2bf(f01.x) | ((u32)f2bf(f01.y) << 16);
        vb0.w = (u32)f2bf(f01.z) | ((u32)f2bf(f01.w) << 16);
        vb1.x = (u32)f2bf(f10.x) | ((u32)f2bf(f10.y) << 16);
        vb1.y = (u32)f2bf(f10.z) | ((u32)f2bf(f10.w) << 16);
        vb1.z = (u32)f2bf(f11.x) | ((u32)f2bf(f11.y) << 16);
        vb1.w = (u32)f2bf(f11.z) | ((u32)f2bf(f11.w) << 16);
        *(uint4*)sB[0] = vb0;
        *(uint4*)sB[1] = vb1;
        __syncthreads();
        bf16x8 af[4], bv[4];
#pragma unroll
        for (int f = 0; f < 4; ++f) af[f] = *(const bf16x8*)(pA0 + (f << 9));
#pragma unroll
        for (int f = 0; f < 4; ++f) bv[f] = *(const bf16x8*)(pB0 + (f << 9));
#pragma unroll
        for (int fi = 0; fi < 4; ++fi)
#pragma unroll
            for (int fj = 0; fj < 4; ++fj)
                acc[fi][fj] = __builtin_amdgcn_mfma_f32_16x16x32_bf16(af[fi], bv[fj], acc[fi][fj], 0, 0, 0);
        __syncthreads();
    }
    const int colb = c0 + (wn << 6) + (lane & 15);
    const int rowb = ij0 + (wm << 6) + ((lane >> 4) << 2);
#pragma unroll
    for (int fi = 0; fi < 4; ++fi) {
        const int row = rowb + (fi << 4);
#pragma unroll
        for (int fj = 0; fj < 4; ++fj) {
            const int col = colb + (fj << 4);
#pragma unroll
            for (int v = 0; v < 4; ++v)
                out[((size_t)((bb << 10) + row + v) << 8) + col] = acc[fi][fj][v];
        }
    }
}

extern "C" void kernel_launch(void* const* d_in, const int* in_sizes, int n_in,
                              void* d_out, int out_size, void* d_ws, size_t ws_size,
                              hipStream_t stream) {
    const float* x  = (const float*)d_in[0];
    const float* w1 = (const float*)d_in[1];
    // d_in[2] = conv1_b : cancels through bn1
    const float* g1 = (const float*)d_in[3];
    // d_in[4] = bn1_b : cancels through bn2 (additive per-c constant -> per-m constant)
    const float* w2 = (const float*)d_in[5];
    // d_in[6] = conv2_b : cancels through bn2
    const float* g2 = (const float*)d_in[7];
    const float* b2 = (const float*)d_in[8];
    float* out = (float*)d_out;
    char* ws = (char*)d_ws;

    // ws layout (~174.3 MB): region0 shared by xp (63.4MB, dead after conv1) and kb (134MB)
    u16* xp  = (u16*)ws;
    u16* kb  = (u16*)ws;
    u16* h   = (u16*)(ws + 134217728);                 // 33.5 MB
    u16* w1t = (u16*)(ws + 134217728 + 33554432);      // 6.4 MB, shared with w2s (dead after conv1)
    u16* w2s = w1t;
    char* sm = ws + 134217728 + 33554432 + 6422528;
    float* s1  = (float*)(sm);
    float* q1  = (float*)(sm + 1024);
    float* s2  = (float*)(sm + 2048);
    float* q2  = (float*)(sm + 6144);
    float* a1  = (float*)(sm + 10240);
    float* a2  = (float*)(sm + 14336);
    float* b2f = (float*)(sm + 18432);

    hipMemsetAsync(sm, 0, 10240, stream);                             // stats accumulators
    hipMemsetAsync(xp, 0, (size_t)NB * PPIX * 256 * 2, stream);       // padded-input zeros
    k_transpose_pad<<<dim3(16, 4, NB), 256, 0, stream>>>(x, xp);
    k_w1prep<<<dim3(256), 256, 0, stream>>>(w1, w1t);
    k_conv1<<<dim3(4, 2, NB), 256, 0, stream>>>(xp, w1t, h, s1, q1);
    k_bn1fin<<<dim3(1), 256, 0, stream>>>(s1, q1, g1, a1);
    k_fold2<<<dim3(1024), 256, 0, stream>>>(w2, a1, w2s);
    k_conv2<<<dim3(8, 8, NB), 256, 0, stream>>>(h, w2s, kb, s2, q2);
    k_bn2fin<<<dim3(4), 256, 0, stream>>>(s2, q2, g2, b2, a2, b2f);
    k_softmax<<<dim3(1024, NB), 256, 0, stream>>>(kb, a2, b2f);
    k_final<<<dim3(8, 2, NB), 256, 0, stream>>>(kb, x, out);
}

// Round 6
// 748.402 us; speedup vs baseline: 1.2719x; 1.2026x over previous
//
#include <hip/hip_runtime.h>

typedef unsigned short u16;
typedef unsigned int u32;
typedef short bf16x8 __attribute__((ext_vector_type(8)));   // 8 bf16 (4 VGPRs)
typedef float f32x4 __attribute__((ext_vector_type(4)));

#define NB   64
#define NC   256
#define NO   256     // conv1 out channels
#define NM   1024    // LF*LF
#define PW   44      // padded width (32 + 2*6)
#define PPIX 1936    // 44*44

__device__ __forceinline__ u16 f2bf(float f) {
    u32 u = __builtin_bit_cast(u32, f);
    u32 r = (u + 0x7FFFu + ((u >> 16) & 1u)) >> 16;   // RNE
    return (u16)r;
}
// async global->LDS, 16B/lane; LDS dest is wave-uniform base + lane*16
__device__ __forceinline__ void ld16(const void* g, void* l) {
    __builtin_amdgcn_global_load_lds((const __attribute__((address_space(1))) u32*)g,
                                     (__attribute__((address_space(3))) u32*)l, 16, 0, 0);
}

// ---------- x[b][c][ij] (f32) -> xp[b][padded pix][c] (bf16), zero border (memset'd) ----------
__global__ __launch_bounds__(256) void k_transpose_pad(const float* __restrict__ x, u16* __restrict__ xp) {
    __shared__ u16 tile[64 * 65];
    const int b = blockIdx.z, ij0 = blockIdx.x * 64, c0 = blockIdx.y * 64;
    const int tid = threadIdx.x;
#pragma unroll
    for (int it = 0; it < 16; ++it) {
        int idx = it * 256 + tid;
        int cr = idx >> 6, ijr = idx & 63;
        tile[ijr * 65 + cr] = f2bf(x[((size_t)(b * NC + c0 + cr) << 10) + ij0 + ijr]);
    }
    __syncthreads();
#pragma unroll
    for (int it = 0; it < 16; ++it) {
        int idx = it * 256 + tid;
        int ijr = idx >> 6, cr = idx & 63;
        int pix = ij0 + ijr;
        int i = pix >> 5, j = pix & 31;
        int prow = (i + 6) * PW + (j + 6);
        xp[((size_t)(b * PPIX + prow) << 8) + c0 + cr] = tile[ijr * 65 + cr];
    }
}

// ---------- conv1_w (O,C,7,7) f32 -> w1t[tap][o][c] bf16 ----------
__global__ __launch_bounds__(256) void k_w1prep(const float* __restrict__ w1, u16* __restrict__ w1t) {
    const int o = blockIdx.x, c = threadIdx.x;
    const float* src = w1 + ((size_t)(o * NC + c)) * 49;
#pragma unroll
    for (int t = 0; t < 49; ++t)
        w1t[((size_t)(t * NO + o) << 8) + c] = f2bf(src[t]);
}

// ---------- conv1: h[b][ij][o] = sum_{tap,c} xp[..][c] * w1t[tap][o][c]; + bn1 stats ----------
// Block tile 256(M=pixels) x 128(N=outch), BK=64 staged as 2 chunks of 32.
// 4 waves as 2x2, each wave 128x64 (acc = 8x4 f32x4 = 128 regs).
// ci (64-ch chunk) is the OUTERMOST loop so consecutive stages are consecutive
// taps with ~95% overlapping A-windows -> reuse distance 1 stage, L2-resident.
__global__ __launch_bounds__(256, 2) void k_conv1(const u16* __restrict__ xp, const u16* __restrict__ w1t,
                                                  u16* __restrict__ h, float* __restrict__ s1, float* __restrict__ q1) {
    __shared__ u16 lsA[2 * 256 * 32];   // [kk][row 256][32]
    __shared__ u16 lsB[2 * 128 * 32];   // [kk][orow 128][32]
    const int tid = threadIdx.x, wv = tid >> 6, lane = tid & 63;
    const int wm = wv & 1, wn = wv >> 1;
    const int bb = blockIdx.z, ij0 = blockIdx.x * 256, o0 = blockIdx.y * 128;

    f32x4 acc[8][4] = {};
    const int lq = lane >> 2, lc8 = (lane & 3) << 3;   // staging: row-in-16 = lane>>2, col = (lane&3)*8

    // A staging: 8 calls/wave/stage (t = kk*4 + tq), rows = wv*64 + tq*16 + lq
    int apix[8];
    u16* dA[8];
#pragma unroll
    for (int t = 0; t < 8; ++t) {
        int kk = t >> 2, tq = t & 3;
        int gr = ij0 + (wv << 6) + (tq << 4) + lq;       // global pixel row of A
        int i = gr >> 5, j = gr & 31;
        apix[t] = ((bb * PPIX + i * PW + j) << 8) + (kk << 5) + lc8;
        dA[t] = lsA + (kk << 13) + (((wv << 6) + (tq << 4)) << 5);
    }
    // B staging: 4 calls/wave/stage (u2 = kk*2 + u), o-rows = wv*32 + u*16 + lq
    int brw[4];
    u16* dB[4];
#pragma unroll
    for (int u2 = 0; u2 < 4; ++u2) {
        int kk = u2 >> 1, u = u2 & 1;
        brw[u2] = ((o0 + (wv << 5) + (u << 4) + lq) << 8) + (kk << 5) + lc8;
        dB[u2] = lsB + (kk << 12) + (((wv << 5) + (u << 4)) << 5);
    }
    // fragment read pointers
    const u16* pA0 = lsA + (((wm << 7) + (lane & 15)) << 5) + ((lane >> 4) << 3);
    const u16* pB0 = lsB + (((wn << 6) + (lane & 15)) << 5) + ((lane >> 4) << 3);

    for (int ci = 0; ci < 4; ++ci) {
        const int coff = ci << 6;                                 // 64-channel chunk offset
        for (int p = 0; p < 7; ++p) {
            for (int q = 0; q < 7; ++q) {
                const int toff = ((p * 2) * PW + q * 2) << 8;     // tap shift in padded image
                const u16* wbase = w1t + ((p * 7 + q) << 16);
#pragma unroll
                for (int t = 0; t < 8; ++t) ld16(xp + apix[t] + toff + coff, dA[t]);
#pragma unroll
                for (int u2 = 0; u2 < 4; ++u2) ld16(wbase + brw[u2] + coff, dB[u2]);
                __syncthreads();
#pragma unroll
                for (int kk = 0; kk < 2; ++kk) {
                    bf16x8 bv[4];
#pragma unroll
                    for (int fj = 0; fj < 4; ++fj)
                        bv[fj] = *(const bf16x8*)(pB0 + (kk << 12) + (fj << 9));
#pragma unroll
                    for (int fi = 0; fi < 8; ++fi) {
                        bf16x8 af = *(const bf16x8*)(pA0 + (kk << 13) + (fi << 9));
#pragma unroll
                        for (int fj = 0; fj < 4; ++fj)
                            acc[fi][fj] = __builtin_amdgcn_mfma_f32_16x16x32_bf16(af, bv[fj], acc[fi][fj], 0, 0, 0);
                    }
                }
                __syncthreads();
            }
        }
    }
    // epilogue: store bf16 h + per-column (o) sum/sumsq for bn1
    const int colb = o0 + (wn << 6) + (lane & 15);
    const int rowb = ij0 + (wm << 7) + ((lane >> 4) << 2);
#pragma unroll
    for (int fj = 0; fj < 4; ++fj) {
        const int col = colb + (fj << 4);
        float s = 0.f, qq = 0.f;
#pragma unroll
        for (int fi = 0; fi < 8; ++fi) {
            const int row = rowb + (fi << 4);
#pragma unroll
            for (int v = 0; v < 4; ++v) {
                float val = acc[fi][fj][v];
                h[((size_t)((bb << 10) + row + v) << 8) + col] = f2bf(val);
                s += val; qq += val * val;
            }
        }
        s += __shfl_xor(s, 16);  s += __shfl_xor(s, 32);
        qq += __shfl_xor(qq, 16); qq += __shfl_xor(qq, 32);
        if (lane < 16) { atomicAdd(&s1[col], s); atomicAdd(&q1[col], qq); }
    }
}

// ---------- bn1 finalize: only the multiplicative part survives (additive shifts cancel in bn2) ----------
__global__ void k_bn1fin(const float* __restrict__ s1, const float* __restrict__ q1,
                         const float* __restrict__ g1, float* __restrict__ a1) {
    const int o = threadIdx.x;
    float mean = s1[o] * (1.f / 65536.f);
    float var  = fmaxf(q1[o] * (1.f / 65536.f) - mean * mean, 0.f);
    a1[o] = g1[o] * rsqrtf(var + 1e-5f);
}

// ---------- fold bn1 scale into conv2 weights: w2s[m][c] = w2[m][c] * a1[c] (bf16) ----------
__global__ __launch_bounds__(256) void k_fold2(const float* __restrict__ w2, const float* __restrict__ a1,
                                               u16* __restrict__ w2s) {
    const int m = blockIdx.x, c = threadIdx.x;
    size_t idx = ((size_t)m << 8) + c;
    w2s[idx] = f2bf(w2[idx] * a1[c]);
}

// ---------- conv2 (1x1): kb[b][ij][m] = sum_c h[b][ij][c]*w2s[m][c]; + bn2 stats ----------
__global__ __launch_bounds__(256) void k_conv2(const u16* __restrict__ h, const u16* __restrict__ w2s,
                                               u16* __restrict__ kb, float* __restrict__ s2, float* __restrict__ q2) {
    __shared__ u16 lsA[128 * 32];
    __shared__ u16 lsB[128 * 32];
    const int tid = threadIdx.x, wv = tid >> 6, lane = tid & 63;
    const int wm = wv & 1, wn = wv >> 1;
    const int bb = blockIdx.z, ij0 = blockIdx.x * 128, m0 = blockIdx.y * 128;

    f32x4 acc[4][4] = {};
    const int lr = lane >> 2, lc8 = (lane & 3) << 3;
    int arow[2], brw[2];
    u16 *dA[2], *dB[2];
#pragma unroll
    for (int u = 0; u < 2; ++u) {
        int r = (wv << 5) + (u << 4) + lr;
        arow[u] = (((bb << 10) + ij0 + r) << 8) + lc8;
        brw[u]  = ((m0 + r) << 8) + lc8;
        dA[u] = lsA + (((wv << 5) + (u << 4)) << 5);
        dB[u] = lsB + (((wv << 5) + (u << 4)) << 5);
    }
    const u16* pA0 = lsA + (((wm << 6) + (lane & 15)) << 5) + ((lane >> 4) << 3);
    const u16* pB0 = lsB + (((wn << 6) + (lane & 15)) << 5) + ((lane >> 4) << 3);

    for (int s = 0; s < 8; ++s) {
        const int cc = s << 5;
#pragma unroll
        for (int u = 0; u < 2; ++u) {
            ld16(h + arow[u] + cc, dA[u]);
            ld16(w2s + brw[u] + cc, dB[u]);
        }
        __syncthreads();
        bf16x8 af[4], bv[4];
#pragma unroll
        for (int f = 0; f < 4; ++f) af[f] = *(const bf16x8*)(pA0 + (f << 9));
#pragma unroll
        for (int f = 0; f < 4; ++f) bv[f] = *(const bf16x8*)(pB0 + (f << 9));
#pragma unroll
        for (int fi = 0; fi < 4; ++fi)
#pragma unroll
            for (int fj = 0; fj < 4; ++fj)
                acc[fi][fj] = __builtin_amdgcn_mfma_f32_16x16x32_bf16(af[fi], bv[fj], acc[fi][fj], 0, 0, 0);
        __syncthreads();
    }
    const int colb = m0 + (wn << 6) + (lane & 15);
    const int rowb = ij0 + (wm << 6) + ((lane >> 4) << 2);
#pragma unroll
    for (int fj = 0; fj < 4; ++fj) {
        const int col = colb + (fj << 4);
        float s = 0.f, qq = 0.f;
#pragma unroll
        for (int fi = 0; fi < 4; ++fi) {
            const int row = rowb + (fi << 4);
#pragma unroll
            for (int v = 0; v < 4; ++v) {
                float val = acc[fi][fj][v];
                kb[((size_t)((bb << 10) + row + v) << 10) + col] = f2bf(val);
                s += val; qq += val * val;
            }
        }
        s += __shfl_xor(s, 16);  s += __shfl_xor(s, 32);
        qq += __shfl_xor(qq, 16); qq += __shfl_xor(qq, 32);
        if (lane < 16) { atomicAdd(&s2[col], s); atomicAdd(&q2[col], qq); }
    }
}

__global__ void k_bn2fin(const float* __restrict__ s2, const float* __restrict__ q2,
                         const float* __restrict__ g2, const float* __restrict__ b2,
                         float* __restrict__ a2, float* __restrict__ b2f) {
    const int m = blockIdx.x * 256 + threadIdx.x;
    float mean = s2[m] * (1.f / 65536.f);
    float var  = fmaxf(q2[m] * (1.f / 65536.f) - mean * mean, 0.f);
    float a = g2[m] * rsqrtf(var + 1e-5f);
    a2[m] = a;
    b2f[m] = b2[m] - mean * a;
}

// ---------- softmax over m (1024) per (b,ij) row, bn2 affine applied, in place ----------
__global__ __launch_bounds__(256) void k_softmax(u16* __restrict__ kb,
                                                 const float* __restrict__ a2, const float* __restrict__ b2f) {
    __shared__ float redm[4], reds[4];
    const int row = (blockIdx.y << 10) + blockIdx.x;
    u16* base = kb + ((size_t)row << 10);
    const int tid = threadIdx.x, lane = tid & 63, wv = tid >> 6;
    const int m0 = tid << 2;
    uint2 rw = *(const uint2*)(base + m0);
    float u[4];
    u[0] = __builtin_bit_cast(float, (rw.x & 0xFFFFu) << 16);
    u[1] = __builtin_bit_cast(float, rw.x & 0xFFFF0000u);
    u[2] = __builtin_bit_cast(float, (rw.y & 0xFFFFu) << 16);
    u[3] = __builtin_bit_cast(float, rw.y & 0xFFFF0000u);
#pragma unroll
    for (int i = 0; i < 4; ++i) u[i] = a2[m0 + i] * u[i] + b2f[m0 + i];
    float mx = fmaxf(fmaxf(u[0], u[1]), fmaxf(u[2], u[3]));
#pragma unroll
    for (int off = 32; off; off >>= 1) mx = fmaxf(mx, __shfl_xor(mx, off));
    if (lane == 0) redm[wv] = mx;
    __syncthreads();
    mx = fmaxf(fmaxf(redm[0], redm[1]), fmaxf(redm[2], redm[3]));
    float e[4], s = 0.f;
#pragma unroll
    for (int i = 0; i < 4; ++i) { e[i] = __expf(u[i] - mx); s += e[i]; }
#pragma unroll
    for (int off = 32; off; off >>= 1) s += __shfl_xor(s, off);
    if (lane == 0) reds[wv] = s;
    __syncthreads();
    float inv = 1.f / (reds[0] + reds[1] + reds[2] + reds[3]);
    u32 o0 = (u32)f2bf(e[0] * inv) | ((u32)f2bf(e[1] * inv) << 16);
    u32 o1 = (u32)f2bf(e[2] * inv) | ((u32)f2bf(e[3] * inv) << 16);
    *(uint2*)(base + m0) = make_uint2(o0, o1);
}

// ---------- final: out[b][ij][c] = sum_m ksm[b][ij][m] * x[b][c][m]; x is f32, out f32 ----------
__global__ __launch_bounds__(256) void k_final(const u16* __restrict__ ksm, const float* __restrict__ x,
                                               float* __restrict__ out) {
    __shared__ u16 lsA[128 * 32];
    __shared__ u16 lsB[128 * 32];
    const int tid = threadIdx.x, wv = tid >> 6, lane = tid & 63;
    const int wm = wv & 1, wn = wv >> 1;
    const int bb = blockIdx.z, ij0 = blockIdx.x * 128, c0 = blockIdx.y * 128;

    f32x4 acc[4][4] = {};
    const int lr = lane >> 2, lc8 = (lane & 3) << 3;
    int arow[2], brw[2];
    u16 *dA[2], *sB[2];
#pragma unroll
    for (int u = 0; u < 2; ++u) {
        int r = (wv << 5) + (u << 4) + lr;
        arow[u] = (((bb << 10) + ij0 + r) << 10) + lc8;
        brw[u]  = (((bb << 8) + c0 + r) << 10) + lc8;    // element offset into f32 x
        dA[u] = lsA + (((wv << 5) + (u << 4)) << 5);     // wave-uniform, glld
        sB[u] = lsB + (((wv << 5) + (u << 4) + lr) << 5) + lc8;  // per-lane store slot
    }
    const u16* pA0 = lsA + (((wm << 6) + (lane & 15)) << 5) + ((lane >> 4) << 3);
    const u16* pB0 = lsB + (((wn << 6) + (lane & 15)) << 5) + ((lane >> 4) << 3);

    for (int s = 0; s < 32; ++s) {
        const int cc = s << 5;
#pragma unroll
        for (int u = 0; u < 2; ++u) ld16(ksm + arow[u] + cc, dA[u]);
        float4 f00 = *(const float4*)(x + brw[0] + cc);
        float4 f01 = *(const float4*)(x + brw[0] + cc + 4);
        float4 f10 = *(const float4*)(x + brw[1] + cc);
        float4 f11 = *(const float4*)(x + brw[1] + cc + 4);
        uint4 vb0, vb1;
        vb0.x = (u32)f2bf(f00.x) | ((u32)f2bf(f00.y) << 16);
        vb0.y = (u32)f2bf(f00.z) | ((u32)f2bf(f00.w) << 16);
        vb0.z = (u32)f2bf(f01.x) | ((u32)f2bf(f01.y) << 16);
        vb0.w = (u32)f2bf(f01.z) | ((u32)f2bf(f01.w) << 16);
        vb1.x = (u32)f2bf(f10.x) | ((u32)f2bf(f10.y) << 16);
        vb1.y = (u32)f2bf(f10.z) | ((u32)f2bf(f10.w) << 16);
        vb1.z = (u32)f2bf(f11.x) | ((u32)f2bf(f11.y) << 16);
        vb1.w = (u32)f2bf(f11.z) | ((u32)f2bf(f11.w) << 16);
        *(uint4*)sB[0] = vb0;
        *(uint4*)sB[1] = vb1;
        __syncthreads();
        bf16x8 af[4], bv[4];
#pragma unroll
        for (int f = 0; f < 4; ++f) af[f] = *(const bf16x8*)(pA0 + (f << 9));
#pragma unroll
        for (int f = 0; f < 4; ++f) bv[f] = *(const bf16x8*)(pB0 + (f << 9));
#pragma unroll
        for (int fi = 0; fi < 4; ++fi)
#pragma unroll
            for (int fj = 0; fj < 4; ++fj)
                acc[fi][fj] = __builtin_amdgcn_mfma_f32_16x16x32_bf16(af[fi], bv[fj], acc[fi][fj], 0, 0, 0);
        __syncthreads();
    }
    const int colb = c0 + (wn << 6) + (lane & 15);
    const int rowb = ij0 + (wm << 6) + ((lane >> 4) << 2);
#pragma unroll
    for (int fi = 0; fi < 4; ++fi) {
        const int row = rowb + (fi << 4);
#pragma unroll
        for (int fj = 0; fj < 4; ++fj) {
            const int col = colb + (fj << 4);
#pragma unroll
            for (int v = 0; v < 4; ++v)
                out[((size_t)((bb << 10) + row + v) << 8) + col] = acc[fi][fj][v];
        }
    }
}

extern "C" void kernel_launch(void* const* d_in, const int* in_sizes, int n_in,
                              void* d_out, int out_size, void* d_ws, size_t ws_size,
                              hipStream_t stream) {
    const float* x  = (const float*)d_in[0];
    const float* w1 = (const float*)d_in[1];
    // d_in[2] = conv1_b : cancels through bn1
    const float* g1 = (const float*)d_in[3];
    // d_in[4] = bn1_b : cancels through bn2 (additive per-c constant -> per-m constant)
    const float* w2 = (const float*)d_in[5];
    // d_in[6] = conv2_b : cancels through bn2
    const float* g2 = (const float*)d_in[7];
    const float* b2 = (const float*)d_in[8];
    float* out = (float*)d_out;
    char* ws = (char*)d_ws;

    // ws layout (~174.3 MB): region0 shared by xp (63.4MB, dead after conv1) and kb (134MB)
    u16* xp  = (u16*)ws;
    u16* kb  = (u16*)ws;
    u16* h   = (u16*)(ws + 134217728);                 // 33.5 MB
    u16* w1t = (u16*)(ws + 134217728 + 33554432);      // 6.4 MB, shared with w2s (dead after conv1)
    u16* w2s = w1t;
    char* sm = ws + 134217728 + 33554432 + 6422528;
    float* s1  = (float*)(sm);
    float* q1  = (float*)(sm + 1024);
    float* s2  = (float*)(sm + 2048);
    float* q2  = (float*)(sm + 6144);
    float* a1  = (float*)(sm + 10240);
    float* a2  = (float*)(sm + 14336);
    float* b2f = (float*)(sm + 18432);

    hipMemsetAsync(sm, 0, 10240, stream);                             // stats accumulators
    hipMemsetAsync(xp, 0, (size_t)NB * PPIX * 256 * 2, stream);       // padded-input zeros
    k_transpose_pad<<<dim3(16, 4, NB), 256, 0, stream>>>(x, xp);
    k_w1prep<<<dim3(256), 256, 0, stream>>>(w1, w1t);
    k_conv1<<<dim3(4, 2, NB), 256, 0, stream>>>(xp, w1t, h, s1, q1);
    k_bn1fin<<<dim3(1), 256, 0, stream>>>(s1, q1, g1, a1);
    k_fold2<<<dim3(1024), 256, 0, stream>>>(w2, a1, w2s);
    k_conv2<<<dim3(8, 8, NB), 256, 0, stream>>>(h, w2s, kb, s2, q2);
    k_bn2fin<<<dim3(4), 256, 0, stream>>>(s2, q2, g2, b2, a2, b2f);
    k_softmax<<<dim3(1024, NB), 256, 0, stream>>>(kb, a2, b2f);
    k_final<<<dim3(8, 2, NB), 256, 0, stream>>>(kb, x, out);
}